// Round 4
// baseline (476.957 us; speedup 1.0000x reference)
//
#include <hip/hip_runtime.h>
#include <hip/hip_bf16.h>
#include <math.h>

#define N_NODES 100000
#define N_EDGES 1600000
#define D_FEAT 128
#define HIDDEN 100
#define N_CLASSES 10

#define SCAN_BLOCK 256
#define N_SCAN_BLOCKS ((N_NODES + SCAN_BLOCK - 1) / SCAN_BLOCK)  // 391

#define BSHIFT 8
#define NBUCK ((N_NODES + (1 << BSHIFT) - 1) >> BSHIFT)  // 391 buckets of 256 nodes

// ws layout (4-byte word offsets)
#define OFF_DEGI   0         // int[100000]
#define OFF_ROWPTR 100000    // int[100001]
#define OFF_CURSOR 200004    // int[100000]
#define OFF_BSUM   300004    // int[512]
#define OFF_BCUR   300516    // int[391*16] padded cursors (one 64B line each)
#define OFF_DINV   306772    // float[100000]
#define OFF_CSUM   406772    // float[100000]
#define OFF_SPART  506772    // float[32*100]
#define OFF_CSRC   509972    // int[1600000]
#define OFF_PART   2109972   // uint2[1600000] (even word offset -> 8B aligned)
#define OFF_H1B    5309972   // uint[100000*50] bf16x2 packed
// end: 10,309,972 words ~= 41.2 MB

__device__ inline unsigned pack_bf16x2(float a, float b) {
    unsigned ua = __float_as_uint(a); ua = (ua + 0x7FFFu + ((ua >> 16) & 1u)) >> 16;
    unsigned ub = __float_as_uint(b); ub = (ub + 0x7FFFu + ((ub >> 16) & 1u)) >> 16;
    return ua | (ub << 16);
}
__device__ inline float bf_lo(unsigned p) { return __uint_as_float(p << 16); }
__device__ inline float bf_hi(unsigned p) { return __uint_as_float(p & 0xFFFF0000u); }

__global__ void k_init(int* __restrict__ deg_i, float* __restrict__ csum, float* __restrict__ S_part) {
    int i = blockIdx.x * blockDim.x + threadIdx.x;
    if (i < N_NODES) { deg_i[i] = 0; csum[i] = 0.0f; }
    if (i < 32 * 100) S_part[i] = 0.0f;
}

__global__ void k_deg(const int* __restrict__ dst, int* __restrict__ deg_i) {
    int e = blockIdx.x * blockDim.x + threadIdx.x;
    if (e < N_EDGES) atomicAdd(&deg_i[dst[e]], 1);
}

__global__ void k_dinv(const int* __restrict__ deg_i, float* __restrict__ dinv) {
    int v = blockIdx.x * blockDim.x + threadIdx.x;
    if (v < N_NODES) dinv[v] = rsqrtf((float)(deg_i[v] + 1));  // +1 = self-loop
}

// block-local exclusive scan of deg_i -> rowptr(local), block sums -> bsum
__global__ void k_scan1(const int* __restrict__ deg_i, int* __restrict__ rowptr,
                        int* __restrict__ bsum) {
    __shared__ int sh[SCAN_BLOCK];
    int t = threadIdx.x;
    int i = blockIdx.x * SCAN_BLOCK + t;
    int v = (i < N_NODES) ? deg_i[i] : 0;
    sh[t] = v;
    __syncthreads();
    for (int off = 1; off < SCAN_BLOCK; off <<= 1) {
        int a = (t >= off) ? sh[t - off] : 0;
        __syncthreads();
        sh[t] += a;
        __syncthreads();
    }
    if (i < N_NODES) rowptr[i] = sh[t] - v;
    if (t == SCAN_BLOCK - 1) bsum[blockIdx.x] = sh[t];
}

// parallel exclusive scan of the 391 block sums (single block, 512 threads)
__global__ void k_scan2(int* __restrict__ bsum, int* __restrict__ rowptr) {
    __shared__ int sh[512];
    int t = threadIdx.x;
    int v = (t < N_SCAN_BLOCKS) ? bsum[t] : 0;
    sh[t] = v;
    __syncthreads();
    for (int off = 1; off < 512; off <<= 1) {
        int a = (t >= off) ? sh[t - off] : 0;
        __syncthreads();
        sh[t] += a;
        __syncthreads();
    }
    if (t < N_SCAN_BLOCKS) bsum[t] = sh[t] - v;          // exclusive
    if (t == N_SCAN_BLOCKS - 1) rowptr[N_NODES] = sh[t]; // total == N_EDGES
}

__global__ void k_scan3(int* __restrict__ rowptr, const int* __restrict__ bsum,
                        int* __restrict__ cursor, int* __restrict__ bcur) {
    int i = blockIdx.x * blockDim.x + threadIdx.x;
    if (i < N_NODES) {
        int r = rowptr[i] + bsum[i / SCAN_BLOCK];
        rowptr[i] = r;
        cursor[i] = r;
        if ((i & ((1 << BSHIFT) - 1)) == 0) bcur[(i >> BSHIFT) * 16] = r;  // bucket base cursor
    }
}

// Phase A: partition edges into 256-node dst-buckets (streaming writes),
// fused with csum[src] += dinv[dst].
__global__ void k_part(const int* __restrict__ src, const int* __restrict__ dst,
                       const float* __restrict__ dinv, int* __restrict__ bcur,
                       float* __restrict__ csum, uint2* __restrict__ part) {
    int e = blockIdx.x * blockDim.x + threadIdx.x;
    if (e < N_EDGES) {
        int s = src[e];
        int d = dst[e];
        atomicAdd(&csum[s], dinv[d]);
        int pos = atomicAdd(&bcur[(d >> BSHIFT) * 16], 1);
        part[pos] = make_uint2((unsigned)s, (unsigned)d);
    }
}

// Phase B: exact-position fill; writes confined to each bucket's ~16KB window (L2-resident)
__global__ void k_fill2(const uint2* __restrict__ part, int* __restrict__ cursor,
                        int* __restrict__ csr_src) {
    int i = blockIdx.x * blockDim.x + threadIdx.x;
    if (i < N_EDGES) {
        uint2 p = part[i];
        int pos = atomicAdd(&cursor[p.y], 1);
        csr_src[pos] = (int)p.x;
    }
}

// h1 = x @ W1 -> bf16 packed. 32 rows/block, 4x4 register tile.
#define GROWS 32
__global__ __launch_bounds__(256) void k_gemm(const float* __restrict__ x,
                                              const float* __restrict__ W1,
                                              unsigned* __restrict__ h1b) {
    __shared__ float xs[GROWS * 130];
    int t = threadIdx.x;
    long long r0 = (long long)blockIdx.x * GROWS;
    for (int i = t; i < GROWS * D_FEAT; i += 256) {
        int r = i >> 7, k = i & 127;
        xs[r * 130 + k] = x[(r0 + r) * D_FEAT + k];
    }
    __syncthreads();
    if (t < 200) {
        int g = t % 25;
        int rg = t / 25;
        float acc[4][4];
#pragma unroll
        for (int a = 0; a < 4; ++a)
#pragma unroll
            for (int b = 0; b < 4; ++b) acc[a][b] = 0.0f;
        const float4* Wv = (const float4*)W1;
        for (int k = 0; k < D_FEAT; k += 2) {
            float4 w0 = Wv[k * 25 + g];
            float4 w1 = Wv[(k + 1) * 25 + g];
#pragma unroll
            for (int rr = 0; rr < 4; ++rr) {
                float2 xv = *(const float2*)&xs[(rg * 4 + rr) * 130 + k];
                acc[rr][0] = fmaf(xv.x, w0.x, acc[rr][0]);
                acc[rr][1] = fmaf(xv.x, w0.y, acc[rr][1]);
                acc[rr][2] = fmaf(xv.x, w0.z, acc[rr][2]);
                acc[rr][3] = fmaf(xv.x, w0.w, acc[rr][3]);
                acc[rr][0] = fmaf(xv.y, w1.x, acc[rr][0]);
                acc[rr][1] = fmaf(xv.y, w1.y, acc[rr][1]);
                acc[rr][2] = fmaf(xv.y, w1.z, acc[rr][2]);
                acc[rr][3] = fmaf(xv.y, w1.w, acc[rr][3]);
            }
        }
#pragma unroll
        for (int rr = 0; rr < 4; ++rr) {
            long long row = r0 + rg * 4 + rr;
            uint2 pv;
            pv.x = pack_bf16x2(acc[rr][0], acc[rr][1]);
            pv.y = pack_bf16x2(acc[rr][2], acc[rr][3]);
            *(uint2*)&h1b[row * 50 + 2 * g] = pv;
        }
    }
}

// CSR gather in bf16 + fused relu/c-weight/partial reduce.
#define NPW 8
__global__ __launch_bounds__(128) void k_gather(const int* __restrict__ rowptr,
                                                const int* __restrict__ csr_src,
                                                const float* __restrict__ dinv,
                                                const float* __restrict__ csum,
                                                const unsigned* __restrict__ h1b,
                                                const float* __restrict__ b1,
                                                float* __restrict__ S_part) {
    int wave = threadIdx.x >> 6, lane = threadIdx.x & 63;
    int wid = blockIdx.x * 2 + wave;
    int u = (lane < 50) ? lane : 49;
    float2 bb = *(const float2*)&b1[2 * u];
    float s0 = 0.0f, s1 = 0.0f;
    int vbase = wid * NPW;
#pragma unroll 1
    for (int i = 0; i < NPW; ++i) {
        int v = vbase + i;
        float dv = dinv[v];
        int jb = rowptr[v], je = rowptr[v + 1];
        unsigned sp = h1b[(size_t)v * 50 + u];
        float a0 = 0.0f, a1 = 0.0f;
        int j = jb;
        for (; j + 1 < je; j += 2) {
            int sA = csr_src[j];
            int sB = csr_src[j + 1];
            float wA = dinv[sA];
            float wB = dinv[sB];
            unsigned pA = h1b[(size_t)sA * 50 + u];
            unsigned pB = h1b[(size_t)sB * 50 + u];
            a0 += wA * bf_lo(pA) + wB * bf_lo(pB);
            a1 += wA * bf_hi(pA) + wB * bf_hi(pB);
        }
        if (j < je) {
            int sA = csr_src[j];
            float wA = dinv[sA];
            unsigned pA = h1b[(size_t)sA * 50 + u];
            a0 += wA * bf_lo(pA);
            a1 += wA * bf_hi(pA);
        }
        float dv2 = dv * dv;
        float t0 = fmaxf(dv * a0 + dv2 * bf_lo(sp) + bb.x, 0.0f);
        float t1 = fmaxf(dv * a1 + dv2 * bf_hi(sp) + bb.y, 0.0f);
        float cv = dv * (csum[v] + dv);
        s0 += cv * t0;
        s1 += cv * t1;
    }
    if (lane < 50) {
        float* row = S_part + (wid & 31) * 100;
        atomicAdd(&row[2 * u], s0);
        atomicAdd(&row[2 * u + 1], s1);
    }
}

// reduce S_part -> S, matvec with W2, log_softmax
__global__ void k_final(const float* __restrict__ S_part, const float* __restrict__ W2,
                        const float* __restrict__ b2, float* __restrict__ out) {
    __shared__ float Sl[HIDDEN];
    __shared__ float p[16];
    int t = threadIdx.x;
    if (t < HIDDEN) {
        float s = 0.0f;
        for (int r = 0; r < 32; ++r) s += S_part[r * 100 + t];
        Sl[t] = s;
    }
    __syncthreads();
    if (t < N_CLASSES) {
        float s = 0.0f;
        for (int f = 0; f < HIDDEN; ++f) s += Sl[f] * W2[f * N_CLASSES + t];
        p[t] = s * (1.0f / (float)N_NODES) + b2[t];
    }
    __syncthreads();
    if (t == 0) {
        float m = -INFINITY;
        for (int i = 0; i < N_CLASSES; ++i) m = fmaxf(m, p[i]);
        float se = 0.0f;
        for (int i = 0; i < N_CLASSES; ++i) se += expf(p[i] - m);
        float ls = logf(se);
        for (int i = 0; i < N_CLASSES; ++i) out[i] = p[i] - m - ls;
    }
}

extern "C" void kernel_launch(void* const* d_in, const int* in_sizes, int n_in,
                              void* d_out, int out_size, void* d_ws, size_t ws_size,
                              hipStream_t stream) {
    const float* x  = (const float*)d_in[0];
    const int*   ei = (const int*)d_in[1];
    const float* W1 = (const float*)d_in[2];
    const float* b1 = (const float*)d_in[3];
    const float* W2 = (const float*)d_in[4];
    const float* b2 = (const float*)d_in[5];
    float* out = (float*)d_out;

    const int* src = ei;
    const int* dst = ei + N_EDGES;

    int*      wsi     = (int*)d_ws;
    float*    wsf     = (float*)d_ws;
    int*      deg_i   = wsi + OFF_DEGI;
    int*      rowptr  = wsi + OFF_ROWPTR;
    int*      cursor  = wsi + OFF_CURSOR;
    int*      bsum    = wsi + OFF_BSUM;
    int*      bcur    = wsi + OFF_BCUR;
    float*    dinv    = wsf + OFF_DINV;
    float*    csum    = wsf + OFF_CSUM;
    float*    S_part  = wsf + OFF_SPART;
    int*      csr_src = wsi + OFF_CSRC;
    uint2*    part    = (uint2*)(wsi + OFF_PART);
    unsigned* h1b     = (unsigned*)(wsi + OFF_H1B);

    const int nodeBlocks = (N_NODES + 255) / 256;
    const int edgeBlocks = (N_EDGES + 255) / 256;

    k_init<<<nodeBlocks, 256, 0, stream>>>(deg_i, csum, S_part);
    k_deg<<<edgeBlocks, 256, 0, stream>>>(dst, deg_i);
    k_dinv<<<nodeBlocks, 256, 0, stream>>>(deg_i, dinv);

    k_scan1<<<N_SCAN_BLOCKS, SCAN_BLOCK, 0, stream>>>(deg_i, rowptr, bsum);
    k_scan2<<<1, 512, 0, stream>>>(bsum, rowptr);
    k_scan3<<<nodeBlocks, 256, 0, stream>>>(rowptr, bsum, cursor, bcur);

    k_part<<<edgeBlocks, 256, 0, stream>>>(src, dst, dinv, bcur, csum, part);
    k_fill2<<<edgeBlocks, 256, 0, stream>>>(part, cursor, csr_src);

    k_gemm<<<N_NODES / GROWS, 256, 0, stream>>>(x, W1, h1b);

    k_gather<<<N_NODES / (2 * NPW), 128, 0, stream>>>(rowptr, csr_src, dinv, csum, h1b, b1, S_part);
    k_final<<<1, 128, 0, stream>>>(S_part, W2, b2, out);
}

// Round 5
// 314.485 us; speedup vs baseline: 1.5166x; 1.5166x over previous
//
#include <hip/hip_runtime.h>
#include <hip/hip_bf16.h>
#include <math.h>

#define N_NODES 100000
#define N_EDGES 1600000
#define D_FEAT 128
#define HIDDEN 100
#define N_CLASSES 10

#define NB 391          // dst buckets of 256 nodes
#define ACAP 5120       // arena slots per bucket (mean 4096, +16 sigma)
#define PTILE 8192      // edges per partition block
#define NPBLK ((N_EDGES + PTILE - 1) / PTILE)  // 196

// ws layout (4-byte word offsets)
#define OFF_BCUR   0          // int[391*16] padded cursors
#define OFF_BBASE  6256       // int[400]
#define OFF_SPART  6656       // float[32*100]
#define OFF_CSUM   9856       // float[100000]
#define OFF_DINV   109856     // float[100000]
#define OFF_ROWPTR 209856     // int[100001]
#define OFF_CSRC   309858     // int[1600000]
#define OFF_ARENA  1909858    // uint[391*5120]
#define OFF_H1B    3911778    // uint[100000*50] bf16x2 packed
// end: 8,911,778 words ~= 35.6 MB

__device__ inline unsigned pack_bf16x2(float a, float b) {
    unsigned ua = __float_as_uint(a); ua = (ua + 0x7FFFu + ((ua >> 16) & 1u)) >> 16;
    unsigned ub = __float_as_uint(b); ub = (ub + 0x7FFFu + ((ub >> 16) & 1u)) >> 16;
    return ua | (ub << 16);
}
__device__ inline float bf_lo(unsigned p) { return __uint_as_float(p << 16); }
__device__ inline float bf_hi(unsigned p) { return __uint_as_float(p & 0xFFFF0000u); }

__global__ void k_init(int* __restrict__ bcur, float* __restrict__ csum,
                       float* __restrict__ S_part) {
    int i = blockIdx.x * blockDim.x + threadIdx.x;
    if (i < N_NODES) csum[i] = 0.0f;
    if (i < 32 * 100) S_part[i] = 0.0f;
    if (i < NB) bcur[i * 16] = i * ACAP;
}

// Phase A: partition edges into 391 dst-buckets. Per block: LDS histogram,
// ONE global cursor bump per (block,bucket) reserving a contiguous run,
// then scatter packed records into the block-owned run.
__global__ __launch_bounds__(256) void k_part2(const int* __restrict__ src,
                                               const int* __restrict__ dst,
                                               int* __restrict__ bcur,
                                               unsigned* __restrict__ arena) {
    __shared__ int hist[NB];
    __shared__ int gbase[NB];
    __shared__ int cur[NB];
    int t = threadIdx.x;
    int e0 = blockIdx.x * PTILE;
    int n = N_EDGES - e0; if (n > PTILE) n = PTILE;

    for (int i = t; i < NB; i += 256) hist[i] = 0;
    __syncthreads();
    for (int i = t; i < n; i += 256) {
        int d = dst[e0 + i];
        atomicAdd(&hist[d >> 8], 1);
    }
    __syncthreads();
    for (int b = t; b < NB; b += 256) {
        int c = hist[b];
        gbase[b] = (c > 0) ? atomicAdd(&bcur[b * 16], c) : 0;
        cur[b] = 0;
    }
    __syncthreads();
    for (int i = t; i < n; i += 256) {
        int s = src[e0 + i];
        int d = dst[e0 + i];
        int b = d >> 8;
        int pos = atomicAdd(&cur[b], 1);
        arena[(unsigned)(gbase[b] + pos)] = (unsigned)s | ((unsigned)(d & 255) << 20);
    }
}

// exclusive scan of bucket counts -> bucket bases in csr space
__global__ void k_scan391(const int* __restrict__ bcur, int* __restrict__ bbase,
                          int* __restrict__ rowptr) {
    __shared__ int sh[512];
    int t = threadIdx.x;  // 512 threads
    int c = (t < NB) ? (bcur[t * 16] - t * ACAP) : 0;
    sh[t] = c;
    __syncthreads();
    for (int off = 1; off < 512; off <<= 1) {
        int a = (t >= off) ? sh[t - off] : 0;
        __syncthreads();
        sh[t] += a;
        __syncthreads();
    }
    if (t < NB) bbase[t] = sh[t] - c;
    if (t == NB - 1) rowptr[N_NODES] = sh[t];  // == N_EDGES
}

// Phase B: one block per bucket. LDS histogram -> deg/dinv/rowptr (no global
// atomics), LDS cursors -> exact csr fill into the block-owned 16KB window,
// fused csum[src] += dinv[dst] (dinv of own nodes LDS-resident).
__global__ __launch_bounds__(256) void k_fillB(const unsigned* __restrict__ arena,
                                               const int* __restrict__ bcur,
                                               const int* __restrict__ bbase,
                                               float* __restrict__ dinv,
                                               int* __restrict__ rowptr,
                                               int* __restrict__ csr_src,
                                               float* __restrict__ csum) {
    __shared__ int hist[256];
    __shared__ int sh[256];
    __shared__ int cur[256];
    __shared__ float dloc[256];
    int b = blockIdx.x;
    int t = threadIdx.x;
    int v0 = b << 8;
    int nv = N_NODES - v0; if (nv > 256) nv = 256;
    int cnt = bcur[b * 16] - b * ACAP;
    const unsigned* A = arena + (size_t)b * ACAP;

    hist[t] = 0;
    __syncthreads();
    for (int i = t; i < cnt; i += 256) atomicAdd(&hist[A[i] >> 20], 1);
    __syncthreads();
    int h = hist[t];
    float dv = 0.0f;
    if (t < nv) {
        dv = rsqrtf((float)(h + 1));  // +1 self-loop
        dinv[v0 + t] = dv;
    }
    dloc[t] = dv;
    sh[t] = h;
    __syncthreads();
    for (int off = 1; off < 256; off <<= 1) {
        int a = (t >= off) ? sh[t - off] : 0;
        __syncthreads();
        sh[t] += a;
        __syncthreads();
    }
    int excl = sh[t] - h;
    int base = bbase[b];
    if (t < nv) rowptr[v0 + t] = base + excl;
    cur[t] = excl;
    __syncthreads();
    for (int i = t; i < cnt; i += 256) {
        unsigned p = A[i];
        int dl = (int)(p >> 20);
        int s = (int)(p & 0xFFFFFu);
        int pos = atomicAdd(&cur[dl], 1);
        csr_src[base + pos] = s;
        atomicAdd(&csum[s], dloc[dl]);
    }
}

// h1 = x @ W1 -> bf16 packed. 32 rows/block, 4x4 register tile.
#define GROWS 32
__global__ __launch_bounds__(256) void k_gemm(const float* __restrict__ x,
                                              const float* __restrict__ W1,
                                              unsigned* __restrict__ h1b) {
    __shared__ float xs[GROWS * 130];
    int t = threadIdx.x;
    long long r0 = (long long)blockIdx.x * GROWS;
    for (int i = t; i < GROWS * D_FEAT; i += 256) {
        int r = i >> 7, k = i & 127;
        xs[r * 130 + k] = x[(r0 + r) * D_FEAT + k];
    }
    __syncthreads();
    if (t < 200) {
        int g = t % 25;
        int rg = t / 25;
        float acc[4][4];
#pragma unroll
        for (int a = 0; a < 4; ++a)
#pragma unroll
            for (int b = 0; b < 4; ++b) acc[a][b] = 0.0f;
        const float4* Wv = (const float4*)W1;
        for (int k = 0; k < D_FEAT; k += 2) {
            float4 w0 = Wv[k * 25 + g];
            float4 w1 = Wv[(k + 1) * 25 + g];
#pragma unroll
            for (int rr = 0; rr < 4; ++rr) {
                float2 xv = *(const float2*)&xs[(rg * 4 + rr) * 130 + k];
                acc[rr][0] = fmaf(xv.x, w0.x, acc[rr][0]);
                acc[rr][1] = fmaf(xv.x, w0.y, acc[rr][1]);
                acc[rr][2] = fmaf(xv.x, w0.z, acc[rr][2]);
                acc[rr][3] = fmaf(xv.x, w0.w, acc[rr][3]);
                acc[rr][0] = fmaf(xv.y, w1.x, acc[rr][0]);
                acc[rr][1] = fmaf(xv.y, w1.y, acc[rr][1]);
                acc[rr][2] = fmaf(xv.y, w1.z, acc[rr][2]);
                acc[rr][3] = fmaf(xv.y, w1.w, acc[rr][3]);
            }
        }
#pragma unroll
        for (int rr = 0; rr < 4; ++rr) {
            long long row = r0 + rg * 4 + rr;
            uint2 pv;
            pv.x = pack_bf16x2(acc[rr][0], acc[rr][1]);
            pv.y = pack_bf16x2(acc[rr][2], acc[rr][3]);
            *(uint2*)&h1b[row * 50 + 2 * g] = pv;
        }
    }
}

// CSR gather in bf16 + fused relu/c-weight/partial reduce.
#define NPW 8
__global__ __launch_bounds__(128) void k_gather(const int* __restrict__ rowptr,
                                                const int* __restrict__ csr_src,
                                                const float* __restrict__ dinv,
                                                const float* __restrict__ csum,
                                                const unsigned* __restrict__ h1b,
                                                const float* __restrict__ b1,
                                                float* __restrict__ S_part) {
    int wave = threadIdx.x >> 6, lane = threadIdx.x & 63;
    int wid = blockIdx.x * 2 + wave;
    int u = (lane < 50) ? lane : 49;
    float2 bb = *(const float2*)&b1[2 * u];
    float s0 = 0.0f, s1 = 0.0f;
    int vbase = wid * NPW;
#pragma unroll 1
    for (int i = 0; i < NPW; ++i) {
        int v = vbase + i;
        float dv = dinv[v];
        int jb = rowptr[v], je = rowptr[v + 1];
        unsigned sp = h1b[(size_t)v * 50 + u];
        float a0 = 0.0f, a1 = 0.0f;
        int j = jb;
        for (; j + 1 < je; j += 2) {
            int sA = csr_src[j];
            int sB = csr_src[j + 1];
            float wA = dinv[sA];
            float wB = dinv[sB];
            unsigned pA = h1b[(size_t)sA * 50 + u];
            unsigned pB = h1b[(size_t)sB * 50 + u];
            a0 += wA * bf_lo(pA) + wB * bf_lo(pB);
            a1 += wA * bf_hi(pA) + wB * bf_hi(pB);
        }
        if (j < je) {
            int sA = csr_src[j];
            float wA = dinv[sA];
            unsigned pA = h1b[(size_t)sA * 50 + u];
            a0 += wA * bf_lo(pA);
            a1 += wA * bf_hi(pA);
        }
        float dv2 = dv * dv;
        float t0 = fmaxf(dv * a0 + dv2 * bf_lo(sp) + bb.x, 0.0f);
        float t1 = fmaxf(dv * a1 + dv2 * bf_hi(sp) + bb.y, 0.0f);
        float cv = dv * (csum[v] + dv);
        s0 += cv * t0;
        s1 += cv * t1;
    }
    if (lane < 50) {
        float* row = S_part + (wid & 31) * 100;
        atomicAdd(&row[2 * u], s0);
        atomicAdd(&row[2 * u + 1], s1);
    }
}

// reduce S_part -> S, matvec with W2, log_softmax
__global__ void k_final(const float* __restrict__ S_part, const float* __restrict__ W2,
                        const float* __restrict__ b2, float* __restrict__ out) {
    __shared__ float Sl[HIDDEN];
    __shared__ float p[16];
    int t = threadIdx.x;
    if (t < HIDDEN) {
        float s = 0.0f;
        for (int r = 0; r < 32; ++r) s += S_part[r * 100 + t];
        Sl[t] = s;
    }
    __syncthreads();
    if (t < N_CLASSES) {
        float s = 0.0f;
        for (int f = 0; f < HIDDEN; ++f) s += Sl[f] * W2[f * N_CLASSES + t];
        p[t] = s * (1.0f / (float)N_NODES) + b2[t];
    }
    __syncthreads();
    if (t == 0) {
        float m = -INFINITY;
        for (int i = 0; i < N_CLASSES; ++i) m = fmaxf(m, p[i]);
        float se = 0.0f;
        for (int i = 0; i < N_CLASSES; ++i) se += expf(p[i] - m);
        float ls = logf(se);
        for (int i = 0; i < N_CLASSES; ++i) out[i] = p[i] - m - ls;
    }
}

extern "C" void kernel_launch(void* const* d_in, const int* in_sizes, int n_in,
                              void* d_out, int out_size, void* d_ws, size_t ws_size,
                              hipStream_t stream) {
    const float* x  = (const float*)d_in[0];
    const int*   ei = (const int*)d_in[1];
    const float* W1 = (const float*)d_in[2];
    const float* b1 = (const float*)d_in[3];
    const float* W2 = (const float*)d_in[4];
    const float* b2 = (const float*)d_in[5];
    float* out = (float*)d_out;

    const int* src = ei;
    const int* dst = ei + N_EDGES;

    int*      wsi     = (int*)d_ws;
    float*    wsf     = (float*)d_ws;
    int*      bcur    = wsi + OFF_BCUR;
    int*      bbase   = wsi + OFF_BBASE;
    float*    S_part  = wsf + OFF_SPART;
    float*    csum    = wsf + OFF_CSUM;
    float*    dinv    = wsf + OFF_DINV;
    int*      rowptr  = wsi + OFF_ROWPTR;
    int*      csr_src = wsi + OFF_CSRC;
    unsigned* arena   = (unsigned*)(wsi + OFF_ARENA);
    unsigned* h1b     = (unsigned*)(wsi + OFF_H1B);

    const int nodeBlocks = (N_NODES + 255) / 256;  // 391

    k_init<<<nodeBlocks, 256, 0, stream>>>(bcur, csum, S_part);
    k_part2<<<NPBLK, 256, 0, stream>>>(src, dst, bcur, arena);
    k_scan391<<<1, 512, 0, stream>>>(bcur, bbase, rowptr);
    k_fillB<<<NB, 256, 0, stream>>>(arena, bcur, bbase, dinv, rowptr, csr_src, csum);

    k_gemm<<<N_NODES / GROWS, 256, 0, stream>>>(x, W1, h1b);

    k_gather<<<N_NODES / (2 * NPW), 128, 0, stream>>>(rowptr, csr_src, dinv, csum, h1b, b1, S_part);
    k_final<<<1, 128, 0, stream>>>(S_part, W2, b2, out);
}

// Round 6
// 271.400 us; speedup vs baseline: 1.7574x; 1.1588x over previous
//
#include <hip/hip_runtime.h>
#include <hip/hip_bf16.h>
#include <math.h>

#define N_NODES 100000
#define N_EDGES 1600000
#define D_FEAT 128
#define HIDDEN 100
#define N_CLASSES 10

#define NB 391          // dst buckets of 256 nodes
#define ACAP 5120       // arena slots per bucket
#define PTILE 8192      // edges per partition block
#define NPBLK ((N_EDGES + PTILE - 1) / PTILE)  // 196

// ws layout (4-byte word offsets)
#define OFF_BCUR   0          // int[391*16]
#define OFF_BBASE  6256       // int[400]
#define OFF_SPART  6656       // float[64*100]
#define OFF_CSUM   13056      // float[100000]
#define OFF_DINV   113056     // float[100000]
#define OFF_ROWPTR 213056     // int[100001] (+1 pad)
#define OFF_CSRC   313058     // int[1600000]
#define OFF_ARENA  1913058    // uint[391*5120]
#define OFF_H1F    3914978    // uint[100000*25]  fp8x4 packed rows (100 B/row)
// end: 6,414,978 words ~= 25.7 MB

typedef float v2f __attribute__((ext_vector_type(2)));

#if __has_builtin(__builtin_amdgcn_cvt_pk_f32_fp8) && __has_builtin(__builtin_amdgcn_cvt_pk_fp8_f32)
#define HAVE_FP8_CVT 1
#else
#define HAVE_FP8_CVT 0
#endif

__device__ inline void fp8x2_dec(unsigned short h, float& f0, float& f1) {
#if HAVE_FP8_CVT
    v2f r = __builtin_amdgcn_cvt_pk_f32_fp8((unsigned)h, false);
    f0 = r[0]; f1 = r[1];
#else
    unsigned b0 = h & 0xFFu, b1 = (h >> 8) & 0xFFu;
    float v0 = __uint_as_float((b0 & 0x7Fu) << 20) * 0x1p120f;
    float v1 = __uint_as_float((b1 & 0x7Fu) << 20) * 0x1p120f;
    f0 = (b0 & 0x80u) ? -v0 : v0;
    f1 = (b1 & 0x80u) ? -v1 : v1;
#endif
}

#if !HAVE_FP8_CVT
__device__ inline unsigned fp8_enc1(float f) {
    unsigned s = (__float_as_uint(f) >> 31) << 7;
    float fa = fminf(fabsf(f), 448.0f);
    unsigned b;
    if (fa < 0.015625f) {               // subnormal: multiples of 2^-9
        b = (unsigned)rintf(fa * 512.0f);
    } else {
        unsigned u = __float_as_uint(fa);
        u += 0x7FFFFu + ((u >> 20) & 1u);  // RTNE to 3 mantissa bits
        unsigned e = u >> 23, m = (u >> 20) & 7u;
        b = ((e - 120u) << 3) | m;
        if (b > 0x7Eu) b = 0x7Eu;
    }
    return b | s;
}
#endif

__device__ inline unsigned fp8x4_enc(float a0, float a1, float a2, float a3) {
#if HAVE_FP8_CVT
    unsigned pk = 0;
    pk = __builtin_amdgcn_cvt_pk_fp8_f32(a0, a1, pk, false);
    pk = __builtin_amdgcn_cvt_pk_fp8_f32(a2, a3, pk, true);
    return pk;
#else
    return fp8_enc1(a0) | (fp8_enc1(a1) << 8) | (fp8_enc1(a2) << 16) | (fp8_enc1(a3) << 24);
#endif
}

__global__ void k_init(int* __restrict__ bcur, float* __restrict__ csum,
                       float* __restrict__ S_part) {
    int i = blockIdx.x * blockDim.x + threadIdx.x;
    if (i < N_NODES) csum[i] = 0.0f;
    if (i < 64 * 100) S_part[i] = 0.0f;
    if (i < NB) bcur[i * 16] = i * ACAP;
}

// Phase A: partition edges into 391 dst-buckets (block-owned contiguous runs)
__global__ __launch_bounds__(256) void k_part2(const int* __restrict__ src,
                                               const int* __restrict__ dst,
                                               int* __restrict__ bcur,
                                               unsigned* __restrict__ arena) {
    __shared__ int hist[NB];
    __shared__ int gbase[NB];
    __shared__ int cur[NB];
    int t = threadIdx.x;
    int e0 = blockIdx.x * PTILE;
    int n = N_EDGES - e0; if (n > PTILE) n = PTILE;

    for (int i = t; i < NB; i += 256) hist[i] = 0;
    __syncthreads();
    for (int i = t; i < n; i += 256) {
        int d = dst[e0 + i];
        atomicAdd(&hist[d >> 8], 1);
    }
    __syncthreads();
    for (int b = t; b < NB; b += 256) {
        int c = hist[b];
        gbase[b] = (c > 0) ? atomicAdd(&bcur[b * 16], c) : 0;
        cur[b] = 0;
    }
    __syncthreads();
    for (int i = t; i < n; i += 256) {
        int s = src[e0 + i];
        int d = dst[e0 + i];
        int b = d >> 8;
        int pos = atomicAdd(&cur[b], 1);
        arena[(unsigned)(gbase[b] + pos)] = (unsigned)s | ((unsigned)(d & 255) << 20);
    }
}

__global__ void k_scan391(const int* __restrict__ bcur, int* __restrict__ bbase,
                          int* __restrict__ rowptr) {
    __shared__ int sh[512];
    int t = threadIdx.x;
    int c = (t < NB) ? (bcur[t * 16] - t * ACAP) : 0;
    sh[t] = c;
    __syncthreads();
    for (int off = 1; off < 512; off <<= 1) {
        int a = (t >= off) ? sh[t - off] : 0;
        __syncthreads();
        sh[t] += a;
        __syncthreads();
    }
    if (t < NB) bbase[t] = sh[t] - c;
    if (t == NB - 1) rowptr[N_NODES] = sh[t];
}

// Phase B: one block per bucket -> deg/dinv/rowptr (LDS hist+scan), exact csr
// fill into block-owned window, fused csum[src] += dinv[dst].
__global__ __launch_bounds__(256) void k_fillB(const unsigned* __restrict__ arena,
                                               const int* __restrict__ bcur,
                                               const int* __restrict__ bbase,
                                               float* __restrict__ dinv,
                                               int* __restrict__ rowptr,
                                               int* __restrict__ csr_src,
                                               float* __restrict__ csum) {
    __shared__ int hist[256];
    __shared__ int sh[256];
    __shared__ int cur[256];
    __shared__ float dloc[256];
    int b = blockIdx.x;
    int t = threadIdx.x;
    int v0 = b << 8;
    int nv = N_NODES - v0; if (nv > 256) nv = 256;
    int cnt = bcur[b * 16] - b * ACAP;
    const unsigned* A = arena + (size_t)b * ACAP;

    hist[t] = 0;
    __syncthreads();
    for (int i = t; i < cnt; i += 256) atomicAdd(&hist[A[i] >> 20], 1);
    __syncthreads();
    int h = hist[t];
    float dv = 0.0f;
    if (t < nv) {
        dv = rsqrtf((float)(h + 1));
        dinv[v0 + t] = dv;
    }
    dloc[t] = dv;
    sh[t] = h;
    __syncthreads();
    for (int off = 1; off < 256; off <<= 1) {
        int a = (t >= off) ? sh[t - off] : 0;
        __syncthreads();
        sh[t] += a;
        __syncthreads();
    }
    int excl = sh[t] - h;
    int base = bbase[b];
    if (t < nv) rowptr[v0 + t] = base + excl;
    cur[t] = excl;
    __syncthreads();
    for (int i = t; i < cnt; i += 256) {
        unsigned p = A[i];
        int dl = (int)(p >> 20);
        int s = (int)(p & 0xFFFFFu);
        int pos = atomicAdd(&cur[dl], 1);
        csr_src[base + pos] = s;
        atomicAdd(&csum[s], dloc[dl]);
    }
}

// h1s = dinv * (x @ W1) -> fp8 e4m3 packed (100 B/row). 32 rows/block.
#define GROWS 32
__global__ __launch_bounds__(256) void k_gemm(const float* __restrict__ x,
                                              const float* __restrict__ W1,
                                              const float* __restrict__ dinv,
                                              unsigned* __restrict__ h1f) {
    __shared__ float xs[GROWS * 130];
    __shared__ float dl[GROWS];
    int t = threadIdx.x;
    long long r0 = (long long)blockIdx.x * GROWS;
    for (int i = t; i < GROWS * D_FEAT; i += 256) {
        int r = i >> 7, k = i & 127;
        xs[r * 130 + k] = x[(r0 + r) * D_FEAT + k];
    }
    if (t < GROWS) dl[t] = dinv[r0 + t];
    __syncthreads();
    if (t < 200) {
        int g = t % 25;
        int rg = t / 25;
        float acc[4][4];
#pragma unroll
        for (int a = 0; a < 4; ++a)
#pragma unroll
            for (int b = 0; b < 4; ++b) acc[a][b] = 0.0f;
        const float4* Wv = (const float4*)W1;
        for (int k = 0; k < D_FEAT; k += 2) {
            float4 w0 = Wv[k * 25 + g];
            float4 w1 = Wv[(k + 1) * 25 + g];
#pragma unroll
            for (int rr = 0; rr < 4; ++rr) {
                float2 xv = *(const float2*)&xs[(rg * 4 + rr) * 130 + k];
                acc[rr][0] = fmaf(xv.x, w0.x, acc[rr][0]);
                acc[rr][1] = fmaf(xv.x, w0.y, acc[rr][1]);
                acc[rr][2] = fmaf(xv.x, w0.z, acc[rr][2]);
                acc[rr][3] = fmaf(xv.x, w0.w, acc[rr][3]);
                acc[rr][0] = fmaf(xv.y, w1.x, acc[rr][0]);
                acc[rr][1] = fmaf(xv.y, w1.y, acc[rr][1]);
                acc[rr][2] = fmaf(xv.y, w1.z, acc[rr][2]);
                acc[rr][3] = fmaf(xv.y, w1.w, acc[rr][3]);
            }
        }
#pragma unroll
        for (int rr = 0; rr < 4; ++rr) {
            long long row = r0 + rg * 4 + rr;
            float dv = dl[rg * 4 + rr];
            h1f[row * 25 + g] = fp8x4_enc(acc[rr][0] * dv, acc[rr][1] * dv,
                                          acc[rr][2] * dv, acc[rr][3] * dv);
        }
    }
}

// CSR gather in fp8 + fused relu/c-weight/partial reduce.
// 1 wave per NPW nodes; 50 active lanes, 2 features per lane (1 ushort load).
#define NPW 4
__global__ __launch_bounds__(128) void k_gather(const int* __restrict__ rowptr,
                                                const int* __restrict__ csr_src,
                                                const float* __restrict__ dinv,
                                                const float* __restrict__ csum,
                                                const unsigned short* __restrict__ h1f,
                                                const float* __restrict__ b1,
                                                float* __restrict__ S_part) {
    int wave = threadIdx.x >> 6, lane = threadIdx.x & 63;
    int wid = blockIdx.x * 2 + wave;
    int u = (lane < 50) ? lane : 49;
    float2 bb = *(const float2*)&b1[2 * u];
    float s0 = 0.0f, s1 = 0.0f;
    int vbase = wid * NPW;
#pragma unroll 1
    for (int i = 0; i < NPW; ++i) {
        int v = vbase + i;
        float dv = dinv[v];
        int jb = rowptr[v], je = rowptr[v + 1];
        float a0, a1;
        fp8x2_dec(h1f[(size_t)v * 50 + u], a0, a1);  // self-loop: dv*h1s[v] = dv^2*h1[v]
        int j = jb;
        for (; j + 3 < je; j += 4) {
            int sA = csr_src[j];
            int sB = csr_src[j + 1];
            int sC = csr_src[j + 2];
            int sD = csr_src[j + 3];
            unsigned short pA = h1f[(size_t)sA * 50 + u];
            unsigned short pB = h1f[(size_t)sB * 50 + u];
            unsigned short pC = h1f[(size_t)sC * 50 + u];
            unsigned short pD = h1f[(size_t)sD * 50 + u];
            float f0, f1;
            fp8x2_dec(pA, f0, f1); a0 += f0; a1 += f1;
            fp8x2_dec(pB, f0, f1); a0 += f0; a1 += f1;
            fp8x2_dec(pC, f0, f1); a0 += f0; a1 += f1;
            fp8x2_dec(pD, f0, f1); a0 += f0; a1 += f1;
        }
        for (; j < je; ++j) {
            int sA = csr_src[j];
            float f0, f1;
            fp8x2_dec(h1f[(size_t)sA * 50 + u], f0, f1);
            a0 += f0; a1 += f1;
        }
        float t0 = fmaxf(fmaf(dv, a0, bb.x), 0.0f);
        float t1 = fmaxf(fmaf(dv, a1, bb.y), 0.0f);
        float cv = dv * (csum[v] + dv);
        s0 = fmaf(cv, t0, s0);
        s1 = fmaf(cv, t1, s1);
    }
    if (lane < 50) {
        float* row = S_part + (wid & 63) * 100;
        atomicAdd(&row[2 * u], s0);
        atomicAdd(&row[2 * u + 1], s1);
    }
}

// reduce S_part -> S, matvec with W2, log_softmax
__global__ void k_final(const float* __restrict__ S_part, const float* __restrict__ W2,
                        const float* __restrict__ b2, float* __restrict__ out) {
    __shared__ float Sl[HIDDEN];
    __shared__ float p[16];
    int t = threadIdx.x;
    if (t < HIDDEN) {
        float s = 0.0f;
        for (int r = 0; r < 64; ++r) s += S_part[r * 100 + t];
        Sl[t] = s;
    }
    __syncthreads();
    if (t < N_CLASSES) {
        float s = 0.0f;
        for (int f = 0; f < HIDDEN; ++f) s += Sl[f] * W2[f * N_CLASSES + t];
        p[t] = s * (1.0f / (float)N_NODES) + b2[t];
    }
    __syncthreads();
    if (t == 0) {
        float m = -INFINITY;
        for (int i = 0; i < N_CLASSES; ++i) m = fmaxf(m, p[i]);
        float se = 0.0f;
        for (int i = 0; i < N_CLASSES; ++i) se += expf(p[i] - m);
        float ls = logf(se);
        for (int i = 0; i < N_CLASSES; ++i) out[i] = p[i] - m - ls;
    }
}

extern "C" void kernel_launch(void* const* d_in, const int* in_sizes, int n_in,
                              void* d_out, int out_size, void* d_ws, size_t ws_size,
                              hipStream_t stream) {
    const float* x  = (const float*)d_in[0];
    const int*   ei = (const int*)d_in[1];
    const float* W1 = (const float*)d_in[2];
    const float* b1 = (const float*)d_in[3];
    const float* W2 = (const float*)d_in[4];
    const float* b2 = (const float*)d_in[5];
    float* out = (float*)d_out;

    const int* src = ei;
    const int* dst = ei + N_EDGES;

    int*      wsi     = (int*)d_ws;
    float*    wsf     = (float*)d_ws;
    int*      bcur    = wsi + OFF_BCUR;
    int*      bbase   = wsi + OFF_BBASE;
    float*    S_part  = wsf + OFF_SPART;
    float*    csum    = wsf + OFF_CSUM;
    float*    dinv    = wsf + OFF_DINV;
    int*      rowptr  = wsi + OFF_ROWPTR;
    int*      csr_src = wsi + OFF_CSRC;
    unsigned* arena   = (unsigned*)(wsi + OFF_ARENA);
    unsigned* h1f     = (unsigned*)(wsi + OFF_H1F);

    const int nodeBlocks = (N_NODES + 255) / 256;  // 391

    k_init<<<nodeBlocks, 256, 0, stream>>>(bcur, csum, S_part);
    k_part2<<<NPBLK, 256, 0, stream>>>(src, dst, bcur, arena);
    k_scan391<<<1, 512, 0, stream>>>(bcur, bbase, rowptr);
    k_fillB<<<NB, 256, 0, stream>>>(arena, bcur, bbase, dinv, rowptr, csr_src, csum);

    k_gemm<<<N_NODES / GROWS, 256, 0, stream>>>(x, W1, dinv, h1f);

    k_gather<<<N_NODES / (2 * NPW), 128, 0, stream>>>(rowptr, csr_src, dinv, csum,
                                                      (const unsigned short*)h1f, b1, S_part);
    k_final<<<1, 128, 0, stream>>>(S_part, W2, b2, out);
}

// Round 7
// 229.412 us; speedup vs baseline: 2.0790x; 1.1830x over previous
//
#include <hip/hip_runtime.h>
#include <hip/hip_bf16.h>
#include <math.h>

#define N_NODES 100000
#define N_EDGES 1600000
#define D_FEAT 128
#define HIDDEN 100
#define N_CLASSES 10

#define NB 391          // buckets of 256 nodes
#define ACAP 5120       // arena slots per bucket (mean 4092, +16 sigma)
#define PTILE 8192      // edges per partition block
#define NPBLK ((N_EDGES + PTILE - 1) / PTILE)  // 196

// ws layout (4-byte word offsets)
#define OFF_BCURD  0          // int[391*16]
#define OFF_BCURS  6256       // int[391*16]
#define OFF_BBASE  12512      // int[400]
#define OFF_SPART  12912      // float[64*100]
#define OFF_CSUM   19312      // float[100000]
#define OFF_DINV   119312     // float[100000]
#define OFF_ROWPTR 219312     // int[100001] (+1 pad)
#define OFF_CSRC   319314     // int[1600000]
#define OFF_ARENAD 1919314    // uint[391*5120]
#define OFF_ARENAS 3921234    // uint[391*5120]
#define OFF_H1F    5923154    // uint[100000*25] fp8x4 packed rows (100 B/row)
// end: 8,423,154 words ~= 33.7 MB

typedef float v2f __attribute__((ext_vector_type(2)));

#if __has_builtin(__builtin_amdgcn_cvt_pk_f32_fp8) && __has_builtin(__builtin_amdgcn_cvt_pk_fp8_f32)
#define HAVE_FP8_CVT 1
#else
#define HAVE_FP8_CVT 0
#endif

__device__ inline void fp8x2_dec(unsigned short h, float& f0, float& f1) {
#if HAVE_FP8_CVT
    v2f r = __builtin_amdgcn_cvt_pk_f32_fp8((unsigned)h, false);
    f0 = r[0]; f1 = r[1];
#else
    unsigned b0 = h & 0xFFu, b1 = (h >> 8) & 0xFFu;
    float v0 = __uint_as_float((b0 & 0x7Fu) << 20) * 0x1p120f;
    float v1 = __uint_as_float((b1 & 0x7Fu) << 20) * 0x1p120f;
    f0 = (b0 & 0x80u) ? -v0 : v0;
    f1 = (b1 & 0x80u) ? -v1 : v1;
#endif
}

#if !HAVE_FP8_CVT
__device__ inline unsigned fp8_enc1(float f) {
    unsigned s = (__float_as_uint(f) >> 31) << 7;
    float fa = fminf(fabsf(f), 448.0f);
    unsigned b;
    if (fa < 0.015625f) {
        b = (unsigned)rintf(fa * 512.0f);
    } else {
        unsigned u = __float_as_uint(fa);
        u += 0x7FFFFu + ((u >> 20) & 1u);
        unsigned e = u >> 23, m = (u >> 20) & 7u;
        b = ((e - 120u) << 3) | m;
        if (b > 0x7Eu) b = 0x7Eu;
    }
    return b | s;
}
#endif

__device__ inline unsigned fp8x4_enc(float a0, float a1, float a2, float a3) {
#if HAVE_FP8_CVT
    unsigned pk = 0;
    pk = __builtin_amdgcn_cvt_pk_fp8_f32(a0, a1, pk, false);
    pk = __builtin_amdgcn_cvt_pk_fp8_f32(a2, a3, pk, true);
    return pk;
#else
    return fp8_enc1(a0) | (fp8_enc1(a1) << 8) | (fp8_enc1(a2) << 16) | (fp8_enc1(a3) << 24);
#endif
}

__global__ void k_init(int* __restrict__ bcurD, int* __restrict__ bcurS,
                       float* __restrict__ S_part) {
    int i = blockIdx.x * blockDim.x + threadIdx.x;
    if (i < 64 * 100) S_part[i] = 0.0f;
    if (i < NB) { bcurD[i * 16] = i * ACAP; bcurS[i * 16] = i * ACAP; }
}

// Partition edges into dst-buckets (arenaD: s|dl<<20) AND src-buckets
// (arenaS: d|sl<<20). Block-owned contiguous runs -> streaming writes only.
__global__ __launch_bounds__(256) void k_part2(const int* __restrict__ src,
                                               const int* __restrict__ dst,
                                               int* __restrict__ bcurD,
                                               int* __restrict__ bcurS,
                                               unsigned* __restrict__ arenaD,
                                               unsigned* __restrict__ arenaS) {
    __shared__ int histD[NB], histS[NB];
    __shared__ int gbD[NB], gbS[NB];
    __shared__ int curD[NB], curS[NB];
    int t = threadIdx.x;
    int e0 = blockIdx.x * PTILE;
    int n = N_EDGES - e0; if (n > PTILE) n = PTILE;

    for (int i = t; i < NB; i += 256) { histD[i] = 0; histS[i] = 0; }
    __syncthreads();
    for (int i = t; i < n; i += 256) {
        atomicAdd(&histD[dst[e0 + i] >> 8], 1);
        atomicAdd(&histS[src[e0 + i] >> 8], 1);
    }
    __syncthreads();
    for (int b = t; b < NB; b += 256) {
        int cD = histD[b]; gbD[b] = cD ? atomicAdd(&bcurD[b * 16], cD) : 0; curD[b] = 0;
        int cS = histS[b]; gbS[b] = cS ? atomicAdd(&bcurS[b * 16], cS) : 0; curS[b] = 0;
    }
    __syncthreads();
    for (int i = t; i < n; i += 256) {
        int s = src[e0 + i];
        int d = dst[e0 + i];
        int bD = d >> 8;
        int pD = atomicAdd(&curD[bD], 1);
        arenaD[(unsigned)(gbD[bD] + pD)] = (unsigned)s | ((unsigned)(d & 255) << 20);
        int bS = s >> 8;
        int pS = atomicAdd(&curS[bS], 1);
        arenaS[(unsigned)(gbS[bS] + pS)] = (unsigned)d | ((unsigned)(s & 255) << 20);
    }
}

__global__ void k_scan391(const int* __restrict__ bcurD, int* __restrict__ bbase,
                          int* __restrict__ rowptr) {
    __shared__ int sh[512];
    int t = threadIdx.x;
    int c = (t < NB) ? (bcurD[t * 16] - t * ACAP) : 0;
    sh[t] = c;
    __syncthreads();
    for (int off = 1; off < 512; off <<= 1) {
        int a = (t >= off) ? sh[t - off] : 0;
        __syncthreads();
        sh[t] += a;
        __syncthreads();
    }
    if (t < NB) bbase[t] = sh[t] - c;
    if (t == NB - 1) rowptr[N_NODES] = sh[t];
}

// One block per dst-bucket: LDS hist -> deg/dinv/rowptr, exact csr fill into
// the block-owned 16KB window. NO global atomics.
__global__ __launch_bounds__(256) void k_fillB(const unsigned* __restrict__ arenaD,
                                               const int* __restrict__ bcurD,
                                               const int* __restrict__ bbase,
                                               float* __restrict__ dinv,
                                               int* __restrict__ rowptr,
                                               int* __restrict__ csr_src) {
    __shared__ int hist[256];
    __shared__ int sh[256];
    __shared__ int cur[256];
    int b = blockIdx.x;
    int t = threadIdx.x;
    int v0 = b << 8;
    int nv = N_NODES - v0; if (nv > 256) nv = 256;
    int cnt = bcurD[b * 16] - b * ACAP;
    const unsigned* A = arenaD + (size_t)b * ACAP;

    hist[t] = 0;
    __syncthreads();
    for (int i = t; i < cnt; i += 256) atomicAdd(&hist[A[i] >> 20], 1);
    __syncthreads();
    int h = hist[t];
    if (t < nv) dinv[v0 + t] = rsqrtf((float)(h + 1));  // +1 self-loop
    sh[t] = h;
    __syncthreads();
    for (int off = 1; off < 256; off <<= 1) {
        int a = (t >= off) ? sh[t - off] : 0;
        __syncthreads();
        sh[t] += a;
        __syncthreads();
    }
    int excl = sh[t] - h;
    int base = bbase[b];
    if (t < nv) rowptr[v0 + t] = base + excl;
    cur[t] = excl;
    __syncthreads();
    for (int i = t; i < cnt; i += 256) {
        unsigned p = A[i];
        int pos = atomicAdd(&cur[p >> 20], 1);
        csr_src[base + pos] = (int)(p & 0xFFFFFu);
    }
}

// One block per src-bucket: csum via LDS accumulation (zero global atomics).
__global__ __launch_bounds__(256) void k_csumB(const unsigned* __restrict__ arenaS,
                                               const int* __restrict__ bcurS,
                                               const float* __restrict__ dinv,
                                               float* __restrict__ csum) {
    __shared__ float cs[256];
    int b = blockIdx.x, t = threadIdx.x;
    int cnt = bcurS[b * 16] - b * ACAP;
    const unsigned* A = arenaS + (size_t)b * ACAP;
    cs[t] = 0.0f;
    __syncthreads();
    for (int i = t; i < cnt; i += 256) {
        unsigned p = A[i];
        atomicAdd(&cs[p >> 20], dinv[p & 0xFFFFFu]);
    }
    __syncthreads();
    int v = (b << 8) + t;
    if (v < N_NODES) csum[v] = cs[t];
}

// h1s = dinv * (x @ W1) -> fp8 e4m3 packed (100 B/row). 32 rows/block.
#define GROWS 32
__global__ __launch_bounds__(256) void k_gemm(const float* __restrict__ x,
                                              const float* __restrict__ W1,
                                              const float* __restrict__ dinv,
                                              unsigned* __restrict__ h1f) {
    __shared__ float xs[GROWS * 130];
    __shared__ float dl[GROWS];
    int t = threadIdx.x;
    long long r0 = (long long)blockIdx.x * GROWS;
    for (int i = t; i < GROWS * D_FEAT; i += 256) {
        int r = i >> 7, k = i & 127;
        xs[r * 130 + k] = x[(r0 + r) * D_FEAT + k];
    }
    if (t < GROWS) dl[t] = dinv[r0 + t];
    __syncthreads();
    if (t < 200) {
        int g = t % 25;
        int rg = t / 25;
        float acc[4][4];
#pragma unroll
        for (int a = 0; a < 4; ++a)
#pragma unroll
            for (int b = 0; b < 4; ++b) acc[a][b] = 0.0f;
        const float4* Wv = (const float4*)W1;
        for (int k = 0; k < D_FEAT; k += 2) {
            float4 w0 = Wv[k * 25 + g];
            float4 w1 = Wv[(k + 1) * 25 + g];
#pragma unroll
            for (int rr = 0; rr < 4; ++rr) {
                float2 xv = *(const float2*)&xs[(rg * 4 + rr) * 130 + k];
                acc[rr][0] = fmaf(xv.x, w0.x, acc[rr][0]);
                acc[rr][1] = fmaf(xv.x, w0.y, acc[rr][1]);
                acc[rr][2] = fmaf(xv.x, w0.z, acc[rr][2]);
                acc[rr][3] = fmaf(xv.x, w0.w, acc[rr][3]);
                acc[rr][0] = fmaf(xv.y, w1.x, acc[rr][0]);
                acc[rr][1] = fmaf(xv.y, w1.y, acc[rr][1]);
                acc[rr][2] = fmaf(xv.y, w1.z, acc[rr][2]);
                acc[rr][3] = fmaf(xv.y, w1.w, acc[rr][3]);
            }
        }
#pragma unroll
        for (int rr = 0; rr < 4; ++rr) {
            long long row = r0 + rg * 4 + rr;
            float dv = dl[rg * 4 + rr];
            h1f[row * 25 + g] = fp8x4_enc(acc[rr][0] * dv, acc[rr][1] * dv,
                                          acc[rr][2] * dv, acc[rr][3] * dv);
        }
    }
}

// CSR gather in fp8 + fused relu/c-weight/partial reduce.
#define NPW 4
__global__ __launch_bounds__(128) void k_gather(const int* __restrict__ rowptr,
                                                const int* __restrict__ csr_src,
                                                const float* __restrict__ dinv,
                                                const float* __restrict__ csum,
                                                const unsigned short* __restrict__ h1f,
                                                const float* __restrict__ b1,
                                                float* __restrict__ S_part) {
    int wave = threadIdx.x >> 6, lane = threadIdx.x & 63;
    int wid = blockIdx.x * 2 + wave;
    int u = (lane < 50) ? lane : 49;
    float2 bb = *(const float2*)&b1[2 * u];
    float s0 = 0.0f, s1 = 0.0f;
    int vbase = wid * NPW;
#pragma unroll 1
    for (int i = 0; i < NPW; ++i) {
        int v = vbase + i;
        float dv = dinv[v];
        int jb = rowptr[v], je = rowptr[v + 1];
        float a0, a1;
        fp8x2_dec(h1f[(size_t)v * 50 + u], a0, a1);
        int j = jb;
        for (; j + 3 < je; j += 4) {
            int sA = csr_src[j];
            int sB = csr_src[j + 1];
            int sC = csr_src[j + 2];
            int sD = csr_src[j + 3];
            unsigned short pA = h1f[(size_t)sA * 50 + u];
            unsigned short pB = h1f[(size_t)sB * 50 + u];
            unsigned short pC = h1f[(size_t)sC * 50 + u];
            unsigned short pD = h1f[(size_t)sD * 50 + u];
            float f0, f1;
            fp8x2_dec(pA, f0, f1); a0 += f0; a1 += f1;
            fp8x2_dec(pB, f0, f1); a0 += f0; a1 += f1;
            fp8x2_dec(pC, f0, f1); a0 += f0; a1 += f1;
            fp8x2_dec(pD, f0, f1); a0 += f0; a1 += f1;
        }
        for (; j < je; ++j) {
            int sA = csr_src[j];
            float f0, f1;
            fp8x2_dec(h1f[(size_t)sA * 50 + u], f0, f1);
            a0 += f0; a1 += f1;
        }
        float t0 = fmaxf(fmaf(dv, a0, bb.x), 0.0f);
        float t1 = fmaxf(fmaf(dv, a1, bb.y), 0.0f);
        float cv = dv * (csum[v] + dv);
        s0 = fmaf(cv, t0, s0);
        s1 = fmaf(cv, t1, s1);
    }
    if (lane < 50) {
        float* row = S_part + (wid & 63) * 100;
        atomicAdd(&row[2 * u], s0);
        atomicAdd(&row[2 * u + 1], s1);
    }
}

__global__ void k_final(const float* __restrict__ S_part, const float* __restrict__ W2,
                        const float* __restrict__ b2, float* __restrict__ out) {
    __shared__ float Sl[HIDDEN];
    __shared__ float p[16];
    int t = threadIdx.x;
    if (t < HIDDEN) {
        float s = 0.0f;
        for (int r = 0; r < 64; ++r) s += S_part[r * 100 + t];
        Sl[t] = s;
    }
    __syncthreads();
    if (t < N_CLASSES) {
        float s = 0.0f;
        for (int f = 0; f < HIDDEN; ++f) s += Sl[f] * W2[f * N_CLASSES + t];
        p[t] = s * (1.0f / (float)N_NODES) + b2[t];
    }
    __syncthreads();
    if (t == 0) {
        float m = -INFINITY;
        for (int i = 0; i < N_CLASSES; ++i) m = fmaxf(m, p[i]);
        float se = 0.0f;
        for (int i = 0; i < N_CLASSES; ++i) se += expf(p[i] - m);
        float ls = logf(se);
        for (int i = 0; i < N_CLASSES; ++i) out[i] = p[i] - m - ls;
    }
}

extern "C" void kernel_launch(void* const* d_in, const int* in_sizes, int n_in,
                              void* d_out, int out_size, void* d_ws, size_t ws_size,
                              hipStream_t stream) {
    const float* x  = (const float*)d_in[0];
    const int*   ei = (const int*)d_in[1];
    const float* W1 = (const float*)d_in[2];
    const float* b1 = (const float*)d_in[3];
    const float* W2 = (const float*)d_in[4];
    const float* b2 = (const float*)d_in[5];
    float* out = (float*)d_out;

    const int* src = ei;
    const int* dst = ei + N_EDGES;

    int*      wsi     = (int*)d_ws;
    float*    wsf     = (float*)d_ws;
    int*      bcurD   = wsi + OFF_BCURD;
    int*      bcurS   = wsi + OFF_BCURS;
    int*      bbase   = wsi + OFF_BBASE;
    float*    S_part  = wsf + OFF_SPART;
    float*    csum    = wsf + OFF_CSUM;
    float*    dinv    = wsf + OFF_DINV;
    int*      rowptr  = wsi + OFF_ROWPTR;
    int*      csr_src = wsi + OFF_CSRC;
    unsigned* arenaD  = (unsigned*)(wsi + OFF_ARENAD);
    unsigned* arenaS  = (unsigned*)(wsi + OFF_ARENAS);
    unsigned* h1f     = (unsigned*)(wsi + OFF_H1F);

    const int nodeBlocks = (N_NODES + 255) / 256;  // 391

    k_init<<<nodeBlocks, 256, 0, stream>>>(bcurD, bcurS, S_part);
    k_part2<<<NPBLK, 256, 0, stream>>>(src, dst, bcurD, bcurS, arenaD, arenaS);
    k_scan391<<<1, 512, 0, stream>>>(bcurD, bbase, rowptr);
    k_fillB<<<NB, 256, 0, stream>>>(arenaD, bcurD, bbase, dinv, rowptr, csr_src);
    k_csumB<<<NB, 256, 0, stream>>>(arenaS, bcurS, dinv, csum);

    k_gemm<<<N_NODES / GROWS, 256, 0, stream>>>(x, W1, dinv, h1f);

    k_gather<<<N_NODES / (2 * NPW), 128, 0, stream>>>(rowptr, csr_src, dinv, csum,
                                                      (const unsigned short*)h1f, b1, S_part);
    k_final<<<1, 128, 0, stream>>>(S_part, W2, b2, out);
}